// Round 1
// baseline (121.700 us; speedup 1.0000x reference)
//
#include <hip/hip_runtime.h>

#define DEVINL __device__ __forceinline__

// ---------------------------------------------------------------------------
// Compile-time circuit constants via GF(2) linear-map tracking.
// Physical index p (10 bits): bits 9..4 = lane (6 bits), bits 3..0 = reg (4).
// Logical amplitude index a = A * p (A over GF(2)).  CNOT(c,t) => A row update
// (row[9-t] ^= row[9-c]) with NO data movement.  A 1q gate on wire w pairs
// p with p ^ (A^{-1} e_{9-w}); side bit = parity(row_{9-w}(A) & p).
// ---------------------------------------------------------------------------
struct GC { int laneXor, regXor, rowL, rowR; };
struct Circ { GC g[20]; int sgnL[10], sgnR[10]; };

constexpr Circ build_circ() {
    Circ c{};
    unsigned A[10] = {};
    for (int i = 0; i < 10; ++i) A[i] = 1u << i;
    // layer 0 Rot gates (A = I): mask = row = e_{9-w}
    for (int w = 0; w < 10; ++w) {
        int pos = 9 - w;
        unsigned m = 1u << pos;
        c.g[w] = GC{ int(m >> 4), int(m & 15u), int(m >> 4), int(m & 15u) };
    }
    // layer 0 CNOT ring, range r=1, applied q=0..9 sequentially
    for (int q = 0; q < 10; ++q) { int pc = 9 - q, pt = 9 - ((q + 1) % 10); A[pt] ^= A[pc]; }
    // invert A over GF(2) (Gauss-Jordan on augmented [M | Inv])
    unsigned M[10] = {}, Inv[10] = {};
    for (int i = 0; i < 10; ++i) { M[i] = A[i]; Inv[i] = 1u << i; }
    for (int col = 0; col < 10; ++col) {
        int piv = col;
        while (!((M[piv] >> col) & 1u)) ++piv;
        unsigned tm = M[col]; M[col] = M[piv]; M[piv] = tm;
        unsigned ti = Inv[col]; Inv[col] = Inv[piv]; Inv[piv] = ti;
        for (int r = 0; r < 10; ++r)
            if (r != col && ((M[r] >> col) & 1u)) { M[r] ^= M[col]; Inv[r] ^= Inv[col]; }
    }
    // layer 1 Rot gates: m = A^{-1} e_pos (pos-th column of Inv), row = A[pos]
    for (int w = 0; w < 10; ++w) {
        int pos = 9 - w;
        unsigned m = 0;
        for (int i = 0; i < 10; ++i) m |= ((Inv[i] >> pos) & 1u) << i;
        unsigned row = A[pos];
        c.g[10 + w] = GC{ int(m >> 4), int(m & 15u), int(row >> 4), int(row & 15u) };
    }
    // layer 1 CNOT ring, range r=2
    for (int q = 0; q < 10; ++q) { int pc = 9 - q, pt = 9 - ((q + 2) % 10); A[pt] ^= A[pc]; }
    // output Z-sign parities: wire q -> row 9-q of final A
    for (int q = 0; q < 10; ++q) { unsigned row = A[9 - q]; c.sgnL[q] = int(row >> 4); c.sgnR[q] = int(row & 15u); }
    return c;
}

constexpr Circ CC = build_circ();

// conditional sign flip: s in {0,1}
DEVINL float csign(float v, int s) {
    return __int_as_float(__float_as_int(v) ^ (s << 31));
}

// fetch value of expression from lane (lane ^ XOR), all 64 lanes active.
// XOR in {1,2,3}: DPP quad_perm (VALU pipe).  XOR<32: ds_swizzle BitMode.
// else: ds_bpermute (full 64-lane).
template<int XOR>
DEVINL float lx(float v, int lane) {
    int x = __float_as_int(v);
    int r;
    if constexpr (XOR == 1)      r = __builtin_amdgcn_update_dpp(0, x, 0xB1, 0xF, 0xF, true); // quad_perm [1,0,3,2]
    else if constexpr (XOR == 2) r = __builtin_amdgcn_update_dpp(0, x, 0x4E, 0xF, 0xF, true); // quad_perm [2,3,0,1]
    else if constexpr (XOR == 3) r = __builtin_amdgcn_update_dpp(0, x, 0x1B, 0xF, 0xF, true); // quad_perm [3,2,1,0]
    else if constexpr (XOR < 32) r = __builtin_amdgcn_ds_swizzle(x, 0x1F | (XOR << 10));      // xor mode
    else                         r = __builtin_amdgcn_ds_bpermute((lane ^ XOR) << 2, x);
    return __int_as_float(r);
}

// Apply gates G..19.  mats[G*4..]: u00r,u00i,u01r,u01i (SU(2): u11=conj(u00),
// u10=-conj(u01)).  Side s = sL ^ cR;  cA = (u00r, (-1)^s u00i),
// cB = ((-1)^s u01r, u01i).
template<int G>
DEVINL void gates(float (&ar)[16], float (&ai)[16], const float* __restrict__ mats, int lane) {
    if constexpr (G < 20) {
        constexpr GC gc = CC.g[G];
        float fAr = mats[G * 4 + 0];
        float fAi = mats[G * 4 + 1];
        float fBr = mats[G * 4 + 2];
        float fBi = mats[G * 4 + 3];
        int sL = __popc(unsigned(lane & gc.rowL)) & 1;
        fAi = csign(fAi, sL);
        fBr = csign(fBr, sL);
        float br_[16], bi_[16];
        if constexpr (gc.laneXor == 0) {
            #pragma unroll
            for (int r = 0; r < 16; ++r) { br_[r] = ar[r ^ gc.regXor]; bi_[r] = ai[r ^ gc.regXor]; }
        } else {
            #pragma unroll
            for (int r = 0; r < 16; ++r) {
                br_[r] = lx<gc.laneXor>(ar[r ^ gc.regXor], lane);
                bi_[r] = lx<gc.laneXor>(ai[r ^ gc.regXor], lane);
            }
        }
        #pragma unroll
        for (int r = 0; r < 16; ++r) {
            const int cR = __builtin_popcount(unsigned(gc.rowR & r)) & 1; // folds after unroll
            float a_r = ar[r], a_i = ai[r], b_r = br_[r], b_i = bi_[r];
            float nr, ni;
            if (!cR) {
                nr = fAr * a_r - fAi * a_i + fBr * b_r - fBi * b_i;
                ni = fAr * a_i + fAi * a_r + fBr * b_i + fBi * b_r;
            } else {
                nr = fAr * a_r + fAi * a_i - fBr * b_r - fBi * b_i;
                ni = fAr * a_i - fAi * a_r - fBr * b_i + fBi * b_r;
            }
            ar[r] = nr; ai[r] = ni;
        }
        gates<G + 1>(ar, ai, mats, lane);
    }
}

// Pre-kernel: 20 shared Rot matrices (u00, u01 only) -> d_ws
__global__ void rot_prep(const float* __restrict__ qw, float* __restrict__ mats) {
    int g = threadIdx.x;
    if (g < 20) {
        float phi = qw[g * 3 + 0], th = qw[g * 3 + 1], om = qw[g * 3 + 2];
        float c = cosf(0.5f * th), s = sinf(0.5f * th);
        float apo = 0.5f * (phi + om), amo = 0.5f * (phi - om);
        // u00 = e^{-i apo} c ; u01 = -e^{+i amo} s
        mats[g * 4 + 0] =  cosf(apo) * c;
        mats[g * 4 + 1] = -sinf(apo) * c;
        mats[g * 4 + 2] = -cosf(amo) * s;
        mats[g * 4 + 3] = -sinf(amo) * s;
    }
}

__global__ __launch_bounds__(256) void qsim(const float* __restrict__ x,
                                            const float* __restrict__ mats,
                                            float* __restrict__ out, int B) {
    int tid = blockIdx.x * 256 + threadIdx.x;
    int lane = threadIdx.x & 63;
    int b = __builtin_amdgcn_readfirstlane(tid >> 6);   // wave-uniform sample id
    if (b >= B) return;

    // ---- angle embedding: product state, amp(p) = prod_j (bit_j(p)? sin:cos)
    const float* xb = x + b * 10;          // uniform -> s_load
    float cq[10], sq[10];
    #pragma unroll
    for (int q = 0; q < 10; ++q) {
        float h = 0.5f * xb[q];
        sq[q] = __sinf(h); cq[q] = __cosf(h);
    }
    // lane bit jj (0..5) <-> position jj+4 <-> wire 5-jj
    float lf = 1.f;
    #pragma unroll
    for (int jj = 0; jj < 6; ++jj) {
        int w = 5 - jj;
        lf *= ((lane >> jj) & 1) ? sq[w] : cq[w];
    }
    // reg bit k (0..3) <-> position k <-> wire 9-k
    float t01[4], t23[4];
    #pragma unroll
    for (int v = 0; v < 4; ++v) {
        t01[v] = ((v & 1) ? sq[9] : cq[9]) * ((v >> 1) ? sq[8] : cq[8]);
        t23[v] = ((v & 1) ? sq[7] : cq[7]) * ((v >> 1) ? sq[6] : cq[6]);
    }
    float ar[16], ai[16];
    #pragma unroll
    for (int r = 0; r < 16; ++r) { ar[r] = lf * t01[r & 3] * t23[r >> 2]; ai[r] = 0.f; }

    // ---- 20 Rot gates (CNOTs folded into compile-time index algebra)
    gates<0>(ar, ai, mats, lane);

    // ---- PauliZ expvals: E_q = sum_p |amp|^2 * (-1)^{parity(sgnRow_q & p)}
    float prob[16];
    #pragma unroll
    for (int r = 0; r < 16; ++r) prob[r] = ar[r] * ar[r] + ai[r] * ai[r];

    float e[10];
    #pragma unroll
    for (int q = 0; q < 10; ++q) {
        float t = 0.f;
        #pragma unroll
        for (int r = 0; r < 16; ++r) {
            const int neg = __builtin_popcount(unsigned(CC.sgnR[q] & r)) & 1;
            t = neg ? (t - prob[r]) : (t + prob[r]);
        }
        int sl = __popc(unsigned(lane & CC.sgnL[q])) & 1;
        e[q] = csign(t, sl);
    }
    // xor-butterfly wave reduction (steps 1,2 are DPP; 4,8,16 swizzle; 32 bpermute)
    #pragma unroll
    for (int q = 0; q < 10; ++q) {
        e[q] += lx<1>(e[q], lane);
        e[q] += lx<2>(e[q], lane);
        e[q] += lx<4>(e[q], lane);
        e[q] += lx<8>(e[q], lane);
        e[q] += lx<16>(e[q], lane);
        e[q] += lx<32>(e[q], lane);
    }
    // lanes 0..9 write wire=lane
    float v = e[0];
    #pragma unroll
    for (int q = 1; q < 10; ++q) v = (lane == q) ? e[q] : v;
    if (lane < 10) out[b * 10 + lane] = v;
}

extern "C" void kernel_launch(void* const* d_in, const int* in_sizes, int n_in,
                              void* d_out, int out_size, void* d_ws, size_t ws_size,
                              hipStream_t stream) {
    const float* x  = (const float*)d_in[0];
    const float* qw = (const float*)d_in[1];
    float* out  = (float*)d_out;
    float* mats = (float*)d_ws;                 // 80 floats
    int B = in_sizes[0] / 10;
    hipLaunchKernelGGL(rot_prep, dim3(1), dim3(64), 0, stream, qw, mats);
    int blocks = (B * 64 + 255) / 256;
    hipLaunchKernelGGL(qsim, dim3(blocks), dim3(256), 0, stream, x, mats, out, B);
}

// Round 2
// 95.302 us; speedup vs baseline: 1.2770x; 1.2770x over previous
//
#include <hip/hip_runtime.h>

#define DEVINL __device__ __forceinline__

// ---------------------------------------------------------------------------
// Compile-time circuit constants via GF(2) linear-map tracking.
// Physical index p (10 bits): bits 9..4 = lane (6 bits), bits 3..0 = reg (4).
// Logical amplitude index a = A * p (A over GF(2)).  CNOT(c,t) => A row update
// (row[9-t] ^= row[9-c]) with NO data movement.  A 1q gate on wire w pairs
// p with p ^ (A^{-1} e_{9-w}); side bit = parity(row_{9-w}(A) & p).
//
// Layer-0 Rot gates are NOT applied as full-state gates: the embedding output
// is a product state and 1q gates preserve product structure, so layer 0 is
// folded into per-wire complex factors (see qsim). Only gates 10..19 run.
// ---------------------------------------------------------------------------
struct GC { int laneXor, regXor, rowL, rowR; };
struct Circ { GC g[20]; int sgnL[10], sgnR[10]; };

constexpr Circ build_circ() {
    Circ c{};
    unsigned A[10] = {};
    for (int i = 0; i < 10; ++i) A[i] = 1u << i;
    // layer 0 Rot gates (A = I): mask = row = e_{9-w}  (unused at runtime now)
    for (int w = 0; w < 10; ++w) {
        int pos = 9 - w;
        unsigned m = 1u << pos;
        c.g[w] = GC{ int(m >> 4), int(m & 15u), int(m >> 4), int(m & 15u) };
    }
    // layer 0 CNOT ring, range r=1
    for (int q = 0; q < 10; ++q) { int pc = 9 - q, pt = 9 - ((q + 1) % 10); A[pt] ^= A[pc]; }
    // invert A over GF(2)
    unsigned M[10] = {}, Inv[10] = {};
    for (int i = 0; i < 10; ++i) { M[i] = A[i]; Inv[i] = 1u << i; }
    for (int col = 0; col < 10; ++col) {
        int piv = col;
        while (!((M[piv] >> col) & 1u)) ++piv;
        unsigned tm = M[col]; M[col] = M[piv]; M[piv] = tm;
        unsigned ti = Inv[col]; Inv[col] = Inv[piv]; Inv[piv] = ti;
        for (int r = 0; r < 10; ++r)
            if (r != col && ((M[r] >> col) & 1u)) { M[r] ^= M[col]; Inv[r] ^= Inv[col]; }
    }
    // layer 1 Rot gates: m = A^{-1} e_pos, row = A[pos]
    for (int w = 0; w < 10; ++w) {
        int pos = 9 - w;
        unsigned m = 0;
        for (int i = 0; i < 10; ++i) m |= ((Inv[i] >> pos) & 1u) << i;
        unsigned row = A[pos];
        c.g[10 + w] = GC{ int(m >> 4), int(m & 15u), int(row >> 4), int(row & 15u) };
    }
    // layer 1 CNOT ring, range r=2
    for (int q = 0; q < 10; ++q) { int pc = 9 - q, pt = 9 - ((q + 2) % 10); A[pt] ^= A[pc]; }
    // output Z-sign parities
    for (int q = 0; q < 10; ++q) { unsigned row = A[9 - q]; c.sgnL[q] = int(row >> 4); c.sgnR[q] = int(row & 15u); }
    return c;
}

constexpr Circ CC = build_circ();

DEVINL float csign(float v, int s) {
    return __int_as_float(__float_as_int(v) ^ (s << 31));
}

// lane-xor fetch: DPP quad_perm for 1..3 (VALU pipe), ds_swizzle <32, else bpermute
template<int XOR>
DEVINL float lx(float v, int lane) {
    int x = __float_as_int(v);
    int r;
    if constexpr (XOR == 1)      r = __builtin_amdgcn_update_dpp(0, x, 0xB1, 0xF, 0xF, true);
    else if constexpr (XOR == 2) r = __builtin_amdgcn_update_dpp(0, x, 0x4E, 0xF, 0xF, true);
    else if constexpr (XOR == 3) r = __builtin_amdgcn_update_dpp(0, x, 0x1B, 0xF, 0xF, true);
    else if constexpr (XOR < 32) r = __builtin_amdgcn_ds_swizzle(x, 0x1F | (XOR << 10));
    else                         r = __builtin_amdgcn_ds_bpermute((lane ^ XOR) << 2, x);
    return __int_as_float(r);
}

// Apply gates G..19 (layer 1 only at runtime; G starts at 10).
template<int G>
DEVINL void gates(float (&ar)[16], float (&ai)[16], const float* mats, int lane) {
    if constexpr (G < 20) {
        constexpr GC gc = CC.g[G];
        float fAr = mats[G * 4 + 0];
        float fAi = mats[G * 4 + 1];
        float fBr = mats[G * 4 + 2];
        float fBi = mats[G * 4 + 3];
        int sL = __popc(unsigned(lane & gc.rowL)) & 1;
        fAi = csign(fAi, sL);
        fBr = csign(fBr, sL);
        float br_[16], bi_[16];
        if constexpr (gc.laneXor == 0) {
            #pragma unroll
            for (int r = 0; r < 16; ++r) { br_[r] = ar[r ^ gc.regXor]; bi_[r] = ai[r ^ gc.regXor]; }
        } else {
            #pragma unroll
            for (int r = 0; r < 16; ++r) {
                br_[r] = lx<gc.laneXor>(ar[r ^ gc.regXor], lane);
                bi_[r] = lx<gc.laneXor>(ai[r ^ gc.regXor], lane);
            }
        }
        #pragma unroll
        for (int r = 0; r < 16; ++r) {
            const int cR = __builtin_popcount(unsigned(gc.rowR & r)) & 1;
            float a_r = ar[r], a_i = ai[r], b_r = br_[r], b_i = bi_[r];
            float nr, ni;
            if (!cR) {
                nr = fAr * a_r - fAi * a_i + fBr * b_r - fBi * b_i;
                ni = fAr * a_i + fAi * a_r + fBr * b_i + fBi * b_r;
            } else {
                nr = fAr * a_r + fAi * a_i - fBr * b_r - fBi * b_i;
                ni = fAr * a_i - fAi * a_r - fBr * b_i + fBi * b_r;
            }
            ar[r] = nr; ai[r] = ni;
        }
        gates<G + 1>(ar, ai, mats, lane);
    }
}

__global__ __launch_bounds__(256) void qsim(const float* __restrict__ x,
                                            const float* __restrict__ qw,
                                            float* __restrict__ out, int B) {
    // 20 shared Rot matrices (u00r,u00i,u01r,u01i; SU(2): u11=conj(u00), u10=-conj(u01))
    __shared__ float sm[80];
    {
        int g = threadIdx.x;
        if (g < 20) {
            float phi = qw[g * 3 + 0], th = qw[g * 3 + 1], om = qw[g * 3 + 2];
            float c = cosf(0.5f * th), s = sinf(0.5f * th);
            float apo = 0.5f * (phi + om), amo = 0.5f * (phi - om);
            sm[g * 4 + 0] =  cosf(apo) * c;
            sm[g * 4 + 1] = -sinf(apo) * c;
            sm[g * 4 + 2] = -cosf(amo) * s;
            sm[g * 4 + 3] = -sinf(amo) * s;
        }
    }
    __syncthreads();

    int lane = threadIdx.x & 63;
    int b = __builtin_amdgcn_readfirstlane(blockIdx.x * 4 + (threadIdx.x >> 6));
    if (b >= B) return;

    // ---- embedding + layer-0 Rot folded into per-wire complex factors:
    // |0> --RY(x_w)--> (c,s) --Rot_w--> f_w = (a0, a1) complex 2-vector
    const float* xb = x + b * 10;
    float f0r[10], f0i[10], f1r[10], f1i[10];
    #pragma unroll
    for (int w = 0; w < 10; ++w) {
        float h = 0.5f * xb[w];
        float s = __sinf(h), c = __cosf(h);
        float m0 = sm[w * 4 + 0], m1 = sm[w * 4 + 1], m2 = sm[w * 4 + 2], m3 = sm[w * 4 + 3];
        // a0 = u00*c + u01*s ; a1 = u10*c + u11*s = -conj(u01)*c + conj(u00)*s
        f0r[w] =  m0 * c + m2 * s;
        f0i[w] =  m1 * c + m3 * s;
        f1r[w] = -m2 * c + m0 * s;
        f1i[w] =  m3 * c - m1 * s;
    }

    // lane bit jj (0..5) <-> position jj+4 <-> wire 5-jj : complex lane factor
    float lfr, lfi;
    {
        int bit = lane & 1;
        lfr = bit ? f1r[5] : f0r[5];
        lfi = bit ? f1i[5] : f0i[5];
    }
    #pragma unroll
    for (int jj = 1; jj < 6; ++jj) {
        int w = 5 - jj;
        int bit = (lane >> jj) & 1;
        float pr = bit ? f1r[w] : f0r[w];
        float pi = bit ? f1i[w] : f0i[w];
        float nr = lfr * pr - lfi * pi;
        float ni = lfr * pi + lfi * pr;
        lfr = nr; lfi = ni;
    }
    // reg bit k (0..3) <-> position k <-> wire 9-k
    float t01r[4], t01i[4], t23r[4], t23i[4];
    #pragma unroll
    for (int v = 0; v < 4; ++v) {
        float ar9 = (v & 1) ? f1r[9] : f0r[9], ai9 = (v & 1) ? f1i[9] : f0i[9];
        float ar8 = (v >> 1) ? f1r[8] : f0r[8], ai8 = (v >> 1) ? f1i[8] : f0i[8];
        t01r[v] = ar9 * ar8 - ai9 * ai8;
        t01i[v] = ar9 * ai8 + ai9 * ar8;
        float ar7 = (v & 1) ? f1r[7] : f0r[7], ai7 = (v & 1) ? f1i[7] : f0i[7];
        float ar6 = (v >> 1) ? f1r[6] : f0r[6], ai6 = (v >> 1) ? f1i[6] : f0i[6];
        t23r[v] = ar7 * ar6 - ai7 * ai6;
        t23i[v] = ar7 * ai6 + ai7 * ar6;
    }
    // g4 = lf * t01 (4 cmul), amp[r] = g4[r&3] * t23[r>>2] (16 cmul)
    float g4r[4], g4i[4];
    #pragma unroll
    for (int v = 0; v < 4; ++v) {
        g4r[v] = lfr * t01r[v] - lfi * t01i[v];
        g4i[v] = lfr * t01i[v] + lfi * t01r[v];
    }
    float ar[16], ai[16];
    #pragma unroll
    for (int r = 0; r < 16; ++r) {
        ar[r] = g4r[r & 3] * t23r[r >> 2] - g4i[r & 3] * t23i[r >> 2];
        ai[r] = g4r[r & 3] * t23i[r >> 2] + g4i[r & 3] * t23r[r >> 2];
    }

    // ---- layer-1 Rot gates (CNOT rings folded into compile-time index algebra)
    gates<10>(ar, ai, sm, lane);

    // ---- PauliZ expvals
    float prob[16];
    #pragma unroll
    for (int r = 0; r < 16; ++r) prob[r] = ar[r] * ar[r] + ai[r] * ai[r];

    float e[10];
    #pragma unroll
    for (int q = 0; q < 10; ++q) {
        float t = 0.f;
        #pragma unroll
        for (int r = 0; r < 16; ++r) {
            const int neg = __builtin_popcount(unsigned(CC.sgnR[q] & r)) & 1;
            t = neg ? (t - prob[r]) : (t + prob[r]);
        }
        int sl = __popc(unsigned(lane & CC.sgnL[q])) & 1;
        e[q] = csign(t, sl);
    }
    #pragma unroll
    for (int q = 0; q < 10; ++q) {
        e[q] += lx<1>(e[q], lane);
        e[q] += lx<2>(e[q], lane);
        e[q] += lx<4>(e[q], lane);
        e[q] += lx<8>(e[q], lane);
        e[q] += lx<16>(e[q], lane);
        e[q] += lx<32>(e[q], lane);
    }
    float v = e[0];
    #pragma unroll
    for (int q = 1; q < 10; ++q) v = (lane == q) ? e[q] : v;
    if (lane < 10) out[b * 10 + lane] = v;
}

extern "C" void kernel_launch(void* const* d_in, const int* in_sizes, int n_in,
                              void* d_out, int out_size, void* d_ws, size_t ws_size,
                              hipStream_t stream) {
    const float* x  = (const float*)d_in[0];
    const float* qw = (const float*)d_in[1];
    float* out = (float*)d_out;
    int B = in_sizes[0] / 10;
    int blocks = (B + 3) / 4;   // 4 samples (waves) per 256-thread block
    hipLaunchKernelGGL(qsim, dim3(blocks), dim3(256), 0, stream, x, qw, out, B);
}